// Round 4
// baseline (142.789 us; speedup 1.0000x reference)
//
#include <hip/hip_runtime.h>
#include <math.h>

#define BN 8192
#define DN 512
#define KN 8
#define WIN 16          // window half-width around sorted position (>= KN, margin for ties)

typedef unsigned long long u64;
typedef unsigned int u32;

// ---- ws layout (bytes) ----
// keys0     : u64  [8192] @ 0
// keys1     : u64  [8192] @ 65536
// sortedIdx : int  [8192] @ 131072
// sortedLab : float[8192] @ 163840
// accum     : float       @ 196608
// ticket    : u32         @ 196612
#define OFF_K0    0
#define OFF_K1    65536
#define OFF_SIDX  131072
#define OFF_SLAB  163840
#define OFF_ACC   196608
#define OFF_TKT   196612

// Order-preserving float->uint transform (all floats).
__device__ __forceinline__ u32 flip_f32(u32 f) {
  return f ^ (u32)(((int)f >> 31) | 0x80000000);
}

__device__ __forceinline__ u64 shfl_xor_u64(u64 v, int mask) {
  u32 lo = (u32)v, hi = (u32)(v >> 32);
  lo = (u32)__shfl_xor((int)lo, mask, 64);
  hi = (u32)__shfl_xor((int)hi, mask, 64);
  return ((u64)hi << 32) | lo;
}

// Merge-path level inside LDS: in has sorted runs of length R (power of 2),
// out gets runs of 2R. 1024 elements, 512 threads -> 2 outputs/thread.
__device__ __forceinline__ void lds_merge(const u64* in, u64* out, int R, int tid) {
  for (int o = tid; o < 1024; o += 512) {
    int off = o & (2 * R - 1);
    const u64* A = in + (o - off);
    const u64* B = A + R;
    int lo = off > R ? off - R : 0;
    int hi = off < R ? off : R;
    while (lo < hi) {
      int m = (lo + hi) >> 1;
      if (A[m] < B[off - m - 1]) lo = m + 1; else hi = m;
    }
    int a = lo, b = off - lo;
    u64 va = (a < R) ? A[a] : ~0ull;
    u64 vb = (b < R) ? B[b] : ~0ull;
    out[o] = va < vb ? va : vb;
  }
}

// ---------------------------------------------------------------------------
// Kernel A: 8 blocks x 512 threads. Each wave register-sorts a 128-element
// run (shuffle bitonic, no barriers), then 3 LDS merge-path levels ->
// sorted 1024-run per block. Block 0 also zeroes accum/ticket.
// ---------------------------------------------------------------------------
__global__ __launch_bounds__(512) void sort1_kernel(const float* __restrict__ L,
                                                    u64* __restrict__ keys,
                                                    float* __restrict__ accum,
                                                    u32* __restrict__ ticket) {
  __shared__ u64 bufA[1024];
  __shared__ u64 bufB[1024];
  const int tid  = threadIdx.x;
  const int lane = tid & 63;
  const int wv   = tid >> 6;                       // 0..7
  const int base = blockIdx.x * 1024 + wv * 128;

  if (blockIdx.x == 0 && tid == 0) { *accum = 0.0f; *ticket = 0u; }

  // element ids: e0 = lane (r=0), e1 = 64+lane (r=1)
  const int g0 = base + lane, g1 = base + 64 + lane;
  u64 v0 = ((u64)flip_f32(__float_as_uint(L[g0])) << 32) | (u32)g0;
  u64 v1 = ((u64)flip_f32(__float_as_uint(L[g1])) << 32) | (u32)g1;

#pragma unroll
  for (int k = 2; k <= 128; k <<= 1) {
#pragma unroll
    for (int j = 64; j > 0; j >>= 1) {
      if (j >= k) continue;                        // only j = k/2 .. 1
      if (j == 64) {                               // k==128: cross-r, ascending
        u64 mn = v0 < v1 ? v0 : v1;
        u64 mx = v0 < v1 ? v1 : v0;
        v0 = mn; v1 = mx;
      } else {
        u64 o0 = shfl_xor_u64(v0, j);
        u64 o1 = shfl_xor_u64(v1, j);
        bool lower = (lane & j) == 0;
        bool up0, up1;
        if (k == 128)     { up0 = true;  up1 = true;  }
        else if (k == 64) { up0 = true;  up1 = false; }
        else { bool u = (lane & k) == 0; up0 = u; up1 = u; }
        bool t0 = (up0 == lower), t1 = (up1 == lower);
        v0 = t0 ? (v0 < o0 ? v0 : o0) : (v0 < o0 ? o0 : v0);
        v1 = t1 ? (v1 < o1 ? v1 : o1) : (v1 < o1 ? o1 : v1);
      }
    }
  }

  bufA[wv * 128 + lane]      = v0;
  bufA[wv * 128 + 64 + lane] = v1;
  __syncthreads();
  lds_merge(bufA, bufB, 128, tid); __syncthreads();
  lds_merge(bufB, bufA, 256, tid); __syncthreads();
  lds_merge(bufA, bufB, 512, tid); __syncthreads();

  keys[blockIdx.x * 1024 + tid]       = bufB[tid];
  keys[blockIdx.x * 1024 + 512 + tid] = bufB[512 + tid];
}

// ---------------------------------------------------------------------------
// Kernel B: global merge-path pass, runs RUN -> 2*RUN. One thread per output.
// FINAL pass emits sortedIdx / sortedLab (unflips the float).
// ---------------------------------------------------------------------------
template <int RUN, bool FINAL>
__global__ __launch_bounds__(256) void merge_pass_kernel(const u64* __restrict__ in,
                                                         u64* __restrict__ outk,
                                                         int* __restrict__ sIdx,
                                                         float* __restrict__ sLab) {
  const int t = blockIdx.x * 256 + threadIdx.x;   // 0..8191
  const int seg = t / (2 * RUN);
  const int o   = t & (2 * RUN - 1);
  const u64* A = in + seg * 2 * RUN;
  const u64* B = A + RUN;

  int lo = (o > RUN) ? (o - RUN) : 0;
  int hi = (o < RUN) ? o : RUN;
  while (lo < hi) {
    int a = (lo + hi) >> 1;
    if (A[a] < B[o - a - 1]) lo = a + 1; else hi = a;
  }
  const int a = lo, b = o - a;
  u64 va = (a < RUN) ? A[a] : ~0ull;
  u64 vb = (b < RUN) ? B[b] : ~0ull;
  u64 v = (va < vb) ? va : vb;

  if (FINAL) {
    u32 f = (u32)(v >> 32);
    u32 orig = (f & 0x80000000u) ? (f ^ 0x80000000u) : ~f;  // unflip
    sIdx[t] = (int)(u32)v;
    sLab[t] = __uint_as_float(orig);
  } else {
    outk[t] = v;
  }
}

// ---------------------------------------------------------------------------
// Kernel C: one wave per sorted position. Fused: window top-8 selection
// (64-lane shuffle bitonic on (distbits||idx) u64 keys -> exact lexicographic
// jax tie semantics), Gaussian weights, neighbor gather, cosine sim, and
// ticket-gated final reduction.
// ---------------------------------------------------------------------------
__global__ __launch_bounds__(256) void wmean_cos_kernel(const float* __restrict__ S,
                                                        const int* __restrict__ sortedIdx,
                                                        const float* __restrict__ sortedLab,
                                                        float* __restrict__ accum,
                                                        u32* __restrict__ ticket,
                                                        float* __restrict__ out) {
  const int tid  = threadIdx.x;
  const int lane = tid & 63;
  const int wv   = tid >> 6;
  const int blk  = blockIdx.x;                       // 0..2047
  const int swz  = ((blk & 7) << 8) | (blk >> 3);    // XCD x -> sorted range [x*1024,(x+1)*1024)
  const int p    = swz * 4 + wv;                     // sorted position
  const int b    = sortedIdx[p];                     // original row
  const float Lb = sortedLab[p];

  // --- selection: lanes 0..32 hold window candidates ---
  u64 key = ~0ull;
  {
    int q = p - WIN + lane;
    if (lane <= 2 * WIN && q >= 0 && q < BN) {
      float dist = fabsf(sortedLab[q] - Lb);         // >= 0: IEEE bits are order-preserving
      key = ((u64)__float_as_uint(dist) << 32) | (u32)sortedIdx[q];
    }
  }
  // 64-lane bitonic sort ascending (21 substeps)
#pragma unroll
  for (int k = 2; k <= 64; k <<= 1) {
#pragma unroll
    for (int j = 32; j > 0; j >>= 1) {
      if (j >= k) continue;
      u64 o = shfl_xor_u64(key, j);
      bool lower = (lane & j) == 0;
      bool up = (k == 64) ? true : ((lane & k) == 0);
      key = (up == lower) ? (key < o ? key : o) : (key < o ? o : key);
    }
  }
  // lanes 0..7 hold the 8 nearest; compute normalized Gaussian weights
  float e = 0.0f;
  if (lane < 8) {
    float d = __uint_as_float((u32)(key >> 32));
    e = expf(-d * d * (1.0f / 50.0f));               // 2*STD^2 = 50; const cancels
  }
  float ssum = e;
  ssum += __shfl_xor(ssum, 1, 64);
  ssum += __shfl_xor(ssum, 2, 64);
  ssum += __shfl_xor(ssum, 4, 64);                   // lanes 0-7: sum of the 8
  float wn = e / ssum;                               // valid on lanes 0-7

  int ix[KN]; float w[KN];
  int myidx = (int)(u32)key;
#pragma unroll
  for (int k = 0; k < KN; k++) {
    ix[k] = __shfl(myidx, k, 64);
    w[k]  = __shfl(wn,    k, 64);
  }

  // --- gather + weighted mean + cosine ---
  const float4* Srow = (const float4*)(S + (size_t)b * DN);
  float4 s0 = Srow[lane];
  float4 s1 = Srow[lane + 64];

  float4 m0 = make_float4(0.f, 0.f, 0.f, 0.f);
  float4 m1 = make_float4(0.f, 0.f, 0.f, 0.f);
#pragma unroll
  for (int k = 0; k < KN; k++) {
    const float4* Nrow = (const float4*)(S + (size_t)ix[k] * DN);
    float4 n0 = Nrow[lane];
    float4 n1 = Nrow[lane + 64];
    float wk = w[k];
    m0.x = fmaf(wk, n0.x, m0.x); m0.y = fmaf(wk, n0.y, m0.y);
    m0.z = fmaf(wk, n0.z, m0.z); m0.w = fmaf(wk, n0.w, m0.w);
    m1.x = fmaf(wk, n1.x, m1.x); m1.y = fmaf(wk, n1.y, m1.y);
    m1.z = fmaf(wk, n1.z, m1.z); m1.w = fmaf(wk, n1.w, m1.w);
  }

  float dot = s0.x * m0.x + s0.y * m0.y + s0.z * m0.z + s0.w * m0.w
            + s1.x * m1.x + s1.y * m1.y + s1.z * m1.z + s1.w * m1.w;
  float ns  = s0.x * s0.x + s0.y * s0.y + s0.z * s0.z + s0.w * s0.w
            + s1.x * s1.x + s1.y * s1.y + s1.z * s1.z + s1.w * s1.w;
  float nm  = m0.x * m0.x + m0.y * m0.y + m0.z * m0.z + m0.w * m0.w
            + m1.x * m1.x + m1.y * m1.y + m1.z * m1.z + m1.w * m1.w;

#pragma unroll
  for (int off = 32; off > 0; off >>= 1) {
    dot += __shfl_down(dot, off, 64);
    ns  += __shfl_down(ns,  off, 64);
    nm  += __shfl_down(nm,  off, 64);
  }

  __shared__ float psim[4];
  if (lane == 0) {
    psim[wv] = dot / ((1e-10f + sqrtf(ns)) * (1e-10f + sqrtf(nm)));
  }
  __syncthreads();
  if (tid == 0) {
    float bsum = psim[0] + psim[1] + psim[2] + psim[3];
    atomicAdd(accum, bsum);
    __threadfence();
    u32 old = atomicAdd(ticket, 1u);
    if (old == 2047u) {                  // last block: all accum adds visible
      __threadfence();
      float tot = atomicAdd(accum, 0.0f);  // atomic read (device scope)
      out[0] = 1.0f - tot * (1.0f / (float)BN);
    }
  }
}

extern "C" void kernel_launch(void* const* d_in, const int* in_sizes, int n_in,
                              void* d_out, int out_size, void* d_ws, size_t ws_size,
                              hipStream_t stream) {
  const float* S = (const float*)d_in[0];  // Struct (8192 x 512) fp32
  const float* L = (const float*)d_in[1];  // Label  (8192)       fp32
  float* out = (float*)d_out;

  char* ws = (char*)d_ws;
  u64*   keys0     = (u64*)  (ws + OFF_K0);
  u64*   keys1     = (u64*)  (ws + OFF_K1);
  int*   sortedIdx = (int*)  (ws + OFF_SIDX);
  float* sortedLab = (float*)(ws + OFF_SLAB);
  float* accum     = (float*)(ws + OFF_ACC);
  u32*   ticket    = (u32*)  (ws + OFF_TKT);

  sort1_kernel<<<8, 512, 0, stream>>>(L, keys0, accum, ticket);
  merge_pass_kernel<1024, false><<<32, 256, 0, stream>>>(keys0, keys1, nullptr, nullptr);
  merge_pass_kernel<2048, false><<<32, 256, 0, stream>>>(keys1, keys0, nullptr, nullptr);
  merge_pass_kernel<4096, true ><<<32, 256, 0, stream>>>(keys0, nullptr, sortedIdx, sortedLab);
  wmean_cos_kernel<<<2048, 256, 0, stream>>>(S, sortedIdx, sortedLab, accum, ticket, out);
}

// Round 5
// 93.199 us; speedup vs baseline: 1.5321x; 1.5321x over previous
//
#include <hip/hip_runtime.h>
#include <math.h>

#define BN 8192
#define DN 512
#define KN 8
#define WIN 16          // window half-width around sorted position (>= KN, margin for ties)

typedef unsigned long long u64;
typedef unsigned int u32;

// ---- ws layout (bytes) ----
// keys0     : u64  [8192] @ 0
// keys1     : u64  [8192] @ 65536
// sortedIdx : int  [8192] @ 131072
// sortedLab : float[8192] @ 163840
// partials  : float[2048] @ 196608
#define OFF_K0    0
#define OFF_K1    65536
#define OFF_SIDX  131072
#define OFF_SLAB  163840
#define OFF_PART  196608

// Order-preserving float->uint transform (all floats).
__device__ __forceinline__ u32 flip_f32(u32 f) {
  return f ^ (u32)(((int)f >> 31) | 0x80000000);
}

__device__ __forceinline__ u64 shfl_xor_u64(u64 v, int mask) {
  u32 lo = (u32)v, hi = (u32)(v >> 32);
  lo = (u32)__shfl_xor((int)lo, mask, 64);
  hi = (u32)__shfl_xor((int)hi, mask, 64);
  return ((u64)hi << 32) | lo;
}

// Merge-path level inside LDS: in has sorted runs of length R (power of 2),
// out gets runs of 2R. 1024 elements, 512 threads -> 2 outputs/thread.
__device__ __forceinline__ void lds_merge(const u64* in, u64* out, int R, int tid) {
  for (int o = tid; o < 1024; o += 512) {
    int off = o & (2 * R - 1);
    const u64* A = in + (o - off);
    const u64* B = A + R;
    int lo = off > R ? off - R : 0;
    int hi = off < R ? off : R;
    while (lo < hi) {
      int m = (lo + hi) >> 1;
      if (A[m] < B[off - m - 1]) lo = m + 1; else hi = m;
    }
    int a = lo, b = off - lo;
    u64 va = (a < R) ? A[a] : ~0ull;
    u64 vb = (b < R) ? B[b] : ~0ull;
    out[o] = va < vb ? va : vb;
  }
}

// ---------------------------------------------------------------------------
// Kernel A: 8 blocks x 512 threads. Each wave register-sorts a 128-element
// run (shuffle bitonic, no barriers), then 3 LDS merge-path levels ->
// sorted 1024-run per block.
// ---------------------------------------------------------------------------
__global__ __launch_bounds__(512) void sort1_kernel(const float* __restrict__ L,
                                                    u64* __restrict__ keys) {
  __shared__ u64 bufA[1024];
  __shared__ u64 bufB[1024];
  const int tid  = threadIdx.x;
  const int lane = tid & 63;
  const int wv   = tid >> 6;                       // 0..7
  const int base = blockIdx.x * 1024 + wv * 128;

  const int g0 = base + lane, g1 = base + 64 + lane;
  u64 v0 = ((u64)flip_f32(__float_as_uint(L[g0])) << 32) | (u32)g0;
  u64 v1 = ((u64)flip_f32(__float_as_uint(L[g1])) << 32) | (u32)g1;

#pragma unroll
  for (int k = 2; k <= 128; k <<= 1) {
#pragma unroll
    for (int j = 64; j > 0; j >>= 1) {
      if (j >= k) continue;                        // only j = k/2 .. 1
      if (j == 64) {                               // k==128: cross-r, ascending
        u64 mn = v0 < v1 ? v0 : v1;
        u64 mx = v0 < v1 ? v1 : v0;
        v0 = mn; v1 = mx;
      } else {
        u64 o0 = shfl_xor_u64(v0, j);
        u64 o1 = shfl_xor_u64(v1, j);
        bool lower = (lane & j) == 0;
        bool up0, up1;
        if (k == 128)     { up0 = true;  up1 = true;  }
        else if (k == 64) { up0 = true;  up1 = false; }
        else { bool u = (lane & k) == 0; up0 = u; up1 = u; }
        bool t0 = (up0 == lower), t1 = (up1 == lower);
        v0 = t0 ? (v0 < o0 ? v0 : o0) : (v0 < o0 ? o0 : v0);
        v1 = t1 ? (v1 < o1 ? v1 : o1) : (v1 < o1 ? o1 : v1);
      }
    }
  }

  bufA[wv * 128 + lane]      = v0;
  bufA[wv * 128 + 64 + lane] = v1;
  __syncthreads();
  lds_merge(bufA, bufB, 128, tid); __syncthreads();
  lds_merge(bufB, bufA, 256, tid); __syncthreads();
  lds_merge(bufA, bufB, 512, tid); __syncthreads();

  keys[blockIdx.x * 1024 + tid]       = bufB[tid];
  keys[blockIdx.x * 1024 + 512 + tid] = bufB[512 + tid];
}

// ---------------------------------------------------------------------------
// Kernel B: global merge-path pass, runs RUN -> 2*RUN. One thread per output.
// FINAL pass emits sortedIdx / sortedLab (unflips the float).
// ---------------------------------------------------------------------------
template <int RUN, bool FINAL>
__global__ __launch_bounds__(256) void merge_pass_kernel(const u64* __restrict__ in,
                                                         u64* __restrict__ outk,
                                                         int* __restrict__ sIdx,
                                                         float* __restrict__ sLab) {
  const int t = blockIdx.x * 256 + threadIdx.x;   // 0..8191
  const int seg = t / (2 * RUN);
  const int o   = t & (2 * RUN - 1);
  const u64* A = in + seg * 2 * RUN;
  const u64* B = A + RUN;

  int lo = (o > RUN) ? (o - RUN) : 0;
  int hi = (o < RUN) ? o : RUN;
  while (lo < hi) {
    int a = (lo + hi) >> 1;
    if (A[a] < B[o - a - 1]) lo = a + 1; else hi = a;
  }
  const int a = lo, b = o - a;
  u64 va = (a < RUN) ? A[a] : ~0ull;
  u64 vb = (b < RUN) ? B[b] : ~0ull;
  u64 v = (va < vb) ? va : vb;

  if (FINAL) {
    u32 f = (u32)(v >> 32);
    u32 orig = (f & 0x80000000u) ? (f ^ 0x80000000u) : ~f;  // unflip
    sIdx[t] = (int)(u32)v;
    sLab[t] = __uint_as_float(orig);
  } else {
    outk[t] = v;
  }
}

// ---------------------------------------------------------------------------
// Kernel C: one wave per sorted position. Fused window top-8 selection
// (64-lane shuffle bitonic on (distbits||idx) u64 keys -> exact jax
// lexicographic tie semantics), Gaussian weights, neighbor gather, cosine.
// Tail: ONE partials store per block (atomic tail in R4 cost ~55 us:
// 4096 same-line device atomics + fences serialized at L2).
// ---------------------------------------------------------------------------
__global__ __launch_bounds__(256) void wmean_cos_kernel(const float* __restrict__ S,
                                                        const int* __restrict__ sortedIdx,
                                                        const float* __restrict__ sortedLab,
                                                        float* __restrict__ partials) {
  const int tid  = threadIdx.x;
  const int lane = tid & 63;
  const int wv   = tid >> 6;
  const int blk  = blockIdx.x;                       // 0..2047
  const int swz  = ((blk & 7) << 8) | (blk >> 3);    // XCD x -> sorted range [x*1024,(x+1)*1024)
  const int p    = swz * 4 + wv;                     // sorted position
  const int b    = sortedIdx[p];                     // original row
  const float Lb = sortedLab[p];

  // --- selection: lanes 0..32 hold window candidates ---
  u64 key = ~0ull;
  {
    int q = p - WIN + lane;
    if (lane <= 2 * WIN && q >= 0 && q < BN) {
      float dist = fabsf(sortedLab[q] - Lb);         // >= 0: IEEE bits order-preserving
      key = ((u64)__float_as_uint(dist) << 32) | (u32)sortedIdx[q];
    }
  }
  // 64-lane bitonic sort ascending (21 substeps)
#pragma unroll
  for (int k = 2; k <= 64; k <<= 1) {
#pragma unroll
    for (int j = 32; j > 0; j >>= 1) {
      if (j >= k) continue;
      u64 o = shfl_xor_u64(key, j);
      bool lower = (lane & j) == 0;
      bool up = (k == 64) ? true : ((lane & k) == 0);
      key = (up == lower) ? (key < o ? key : o) : (key < o ? o : key);
    }
  }
  // lanes 0..7 hold the 8 nearest; normalized Gaussian weights
  float e = 0.0f;
  if (lane < 8) {
    float d = __uint_as_float((u32)(key >> 32));
    e = expf(-d * d * (1.0f / 50.0f));               // 2*STD^2 = 50; const cancels
  }
  float ssum = e;
  ssum += __shfl_xor(ssum, 1, 64);
  ssum += __shfl_xor(ssum, 2, 64);
  ssum += __shfl_xor(ssum, 4, 64);                   // lanes 0-7: sum of the 8
  float wn = e / ssum;

  int ix[KN]; float w[KN];
  int myidx = (int)(u32)key;
#pragma unroll
  for (int k = 0; k < KN; k++) {
    ix[k] = __shfl(myidx, k, 64);
    w[k]  = __shfl(wn,    k, 64);
  }

  // --- gather + weighted mean + cosine ---
  const float4* Srow = (const float4*)(S + (size_t)b * DN);
  float4 s0 = Srow[lane];
  float4 s1 = Srow[lane + 64];

  float4 m0 = make_float4(0.f, 0.f, 0.f, 0.f);
  float4 m1 = make_float4(0.f, 0.f, 0.f, 0.f);
#pragma unroll
  for (int k = 0; k < KN; k++) {
    const float4* Nrow = (const float4*)(S + (size_t)ix[k] * DN);
    float4 n0 = Nrow[lane];
    float4 n1 = Nrow[lane + 64];
    float wk = w[k];
    m0.x = fmaf(wk, n0.x, m0.x); m0.y = fmaf(wk, n0.y, m0.y);
    m0.z = fmaf(wk, n0.z, m0.z); m0.w = fmaf(wk, n0.w, m0.w);
    m1.x = fmaf(wk, n1.x, m1.x); m1.y = fmaf(wk, n1.y, m1.y);
    m1.z = fmaf(wk, n1.z, m1.z); m1.w = fmaf(wk, n1.w, m1.w);
  }

  float dot = s0.x * m0.x + s0.y * m0.y + s0.z * m0.z + s0.w * m0.w
            + s1.x * m1.x + s1.y * m1.y + s1.z * m1.z + s1.w * m1.w;
  float ns  = s0.x * s0.x + s0.y * s0.y + s0.z * s0.z + s0.w * s0.w
            + s1.x * s1.x + s1.y * s1.y + s1.z * s1.z + s1.w * s1.w;
  float nm  = m0.x * m0.x + m0.y * m0.y + m0.z * m0.z + m0.w * m0.w
            + m1.x * m1.x + m1.y * m1.y + m1.z * m1.z + m1.w * m1.w;

#pragma unroll
  for (int off = 32; off > 0; off >>= 1) {
    dot += __shfl_down(dot, off, 64);
    ns  += __shfl_down(ns,  off, 64);
    nm  += __shfl_down(nm,  off, 64);
  }

  __shared__ float psim[4];
  if (lane == 0) {
    psim[wv] = dot / ((1e-10f + sqrtf(ns)) * (1e-10f + sqrtf(nm)));
  }
  __syncthreads();
  if (tid == 0) {
    partials[blk] = psim[0] + psim[1] + psim[2] + psim[3];
  }
}

// ---------------------------------------------------------------------------
// Kernel D: reduce 2048 partials -> out[0] = 1 - sum/8192.
// ---------------------------------------------------------------------------
__global__ __launch_bounds__(256) void finalize_kernel(const float* __restrict__ partials,
                                                       float* __restrict__ out) {
  const int tid = threadIdx.x;
  float s = 0.0f;
  for (int i = tid; i < 2048; i += 256) s += partials[i];
#pragma unroll
  for (int off = 32; off > 0; off >>= 1) s += __shfl_down(s, off, 64);
  __shared__ float ps[4];
  if ((tid & 63) == 0) ps[tid >> 6] = s;
  __syncthreads();
  if (tid == 0) {
    float tot = ps[0] + ps[1] + ps[2] + ps[3];
    out[0] = 1.0f - tot * (1.0f / (float)BN);
  }
}

extern "C" void kernel_launch(void* const* d_in, const int* in_sizes, int n_in,
                              void* d_out, int out_size, void* d_ws, size_t ws_size,
                              hipStream_t stream) {
  const float* S = (const float*)d_in[0];  // Struct (8192 x 512) fp32
  const float* L = (const float*)d_in[1];  // Label  (8192)       fp32
  float* out = (float*)d_out;

  char* ws = (char*)d_ws;
  u64*   keys0     = (u64*)  (ws + OFF_K0);
  u64*   keys1     = (u64*)  (ws + OFF_K1);
  int*   sortedIdx = (int*)  (ws + OFF_SIDX);
  float* sortedLab = (float*)(ws + OFF_SLAB);
  float* partials  = (float*)(ws + OFF_PART);

  sort1_kernel<<<8, 512, 0, stream>>>(L, keys0);
  merge_pass_kernel<1024, false><<<32, 256, 0, stream>>>(keys0, keys1, nullptr, nullptr);
  merge_pass_kernel<2048, false><<<32, 256, 0, stream>>>(keys1, keys0, nullptr, nullptr);
  merge_pass_kernel<4096, true ><<<32, 256, 0, stream>>>(keys0, nullptr, sortedIdx, sortedLab);
  wmean_cos_kernel<<<2048, 256, 0, stream>>>(S, sortedIdx, sortedLab, partials);
  finalize_kernel <<<1, 256, 0, stream>>>(partials, out);
}